// Round 1
// baseline (228.464 us; speedup 1.0000x reference)
//
#include <hip/hip_runtime.h>
#include <math.h>

// Problem constants (B=8, T=1024, C=768, 12 heads, hd=64)
constexpr int Bsz  = 8;
constexpr int Tseq = 1024;
constexpr int Cdim = 768;
constexpr int NH   = 12;
constexpr int HD   = 64;
constexpr int Mrows = Bsz * Tseq;   // 8192
constexpr int C3    = 3 * Cdim;     // 2304

using short8  = __attribute__((ext_vector_type(8))) short;
using s4v     = __attribute__((ext_vector_type(4))) short;
using floatx4 = __attribute__((ext_vector_type(4))) float;

__device__ __forceinline__ unsigned short f32_to_bf16_rn(float f) {
    unsigned int u = __float_as_uint(f);
    unsigned int r = u + 0x7FFFu + ((u >> 16) & 1u);
    return (unsigned short)(r >> 16);
}
__device__ __forceinline__ short8 lds_ld8(const unsigned short* p) {
    s4v a = *(const s4v*)p;
    s4v b = *(const s4v*)(p + 4);
    return __builtin_shufflevector(a, b, 0, 1, 2, 3, 4, 5, 6, 7);
}
__device__ __forceinline__ void lds_st8(unsigned short* p, short8 v) {
    *(s4v*)p       = __builtin_shufflevector(v, v, 0, 1, 2, 3);
    *(s4v*)(p + 4) = __builtin_shufflevector(v, v, 4, 5, 6, 7);
}

#define GLOAD_LDS16(g, l) __builtin_amdgcn_global_load_lds(                    \
    (const __attribute__((address_space(1))) void*)(g),                        \
    (__attribute__((address_space(3))) void*)(l), 16, 0, 0)

#define WAITVM6 asm volatile("s_waitcnt vmcnt(6)" ::: "memory")
#define WAITVM0 asm volatile("s_waitcnt vmcnt(0)" ::: "memory")

// ---------------------------------------------------------------------------
// fp32 -> bf16 (round-to-nearest), vectorized.
// ---------------------------------------------------------------------------
__global__ __launch_bounds__(256)
void to_bf16(const float* __restrict__ in, unsigned short* __restrict__ out, int n4)
{
    int t = blockIdx.x * blockDim.x + threadIdx.x;
    if (t >= n4) return;
    float4 v = ((const float4*)in)[t];
    ushort4 o;
    o.x = f32_to_bf16_rn(v.x);
    o.y = f32_to_bf16_rn(v.y);
    o.z = f32_to_bf16_rn(v.z);
    o.w = f32_to_bf16_rn(v.w);
    ((ushort4*)out)[t] = o;
}

// ---------------------------------------------------------------------------
// Transpose fp32 [K][N] -> bf16 [N][K].
// ---------------------------------------------------------------------------
__global__ __launch_bounds__(256)
void transpose_bf16(const float* __restrict__ in, unsigned short* __restrict__ out,
                    int K, int N)
{
    __shared__ float tile[32][33];
    const int k0 = blockIdx.y * 32, n0 = blockIdx.x * 32;
    const int tx = threadIdx.x & 31, ty = threadIdx.x >> 5;
    #pragma unroll
    for (int r = ty; r < 32; r += 8)
        tile[r][tx] = in[(size_t)(k0 + r) * N + n0 + tx];
    __syncthreads();
    #pragma unroll
    for (int r = ty; r < 32; r += 8)
        out[(size_t)(n0 + r) * K + k0 + tx] = f32_to_bf16_rn(tile[tx][r]);
}

// ---------------------------------------------------------------------------
// bf16 GEMM (qkv): C[M,N] = A[M,K] @ B^T + bias, bf16 out.
//
// R10: counted-vmcnt triple-buffered pipeline (T3/T4) + LDS XOR swizzle (T2)
// + setprio (T5) + bijective XCD swizzle (T1).
//   tile BM=256 x BN=128, BK=32, 4 waves, per-wave 128x64 (8x4 frags).
//   LDS = 3 x (16KB A + 8KB B) = 72KB -> 2 blocks/CU.
//   Prefetch distance 2: iter t waits vmcnt(6) (retires tile t's 6 loads,
//   tile t+1 stays in flight), raw s_barrier (no drain), stages tile t+2.
//   vmcnt(0) only on the last K-tile.
//   Swizzle: 16B chunk q of row r lives at q ^ ((r ^ (r>>2)) & 3); applied to
//   the GLOBAL source (linear global_load_lds dest, both-sides rule) and to
//   the ds_read address (folds to a per-lane constant).
// ---------------------------------------------------------------------------
__global__ __launch_bounds__(256, 2)
void gemm_qkv(const unsigned short* __restrict__ A_g,
              const unsigned short* __restrict__ B_g,
              const float* __restrict__ bias,
              unsigned short* __restrict__ Cb,
              int M, int N, int K)
{
    constexpr int BM = 256, BN = 128, BK = 32;
    __shared__ __align__(16) unsigned short Ah[3][BM * BK];
    __shared__ __align__(16) unsigned short Bh[3][BN * BK];

    const int tid  = threadIdx.x;
    const int wave = tid >> 6;
    const int lane = tid & 63;
    const int lm   = lane & 15;
    const int quad = lane >> 4;
    const int wy   = wave >> 1, wx = wave & 1;

    // T1: bijective XCD swizzle (nwg % 8 == 0), then M-major decompose
    const int nby = M / BM;                     // 32 (pow2)
    const int nwg = (N / BN) * nby;
    const int sid = (blockIdx.x & 7) * (nwg >> 3) + (blockIdx.x >> 3);
    const int by  = sid & (nby - 1);
    const int bx  = sid / nby;
    const int row0 = by * BM, col0 = bx * BN;
    const int NI  = K / BK;                     // 24

    // per-lane ds_read swizzle constant: quad ^ f(row), f(r) = (r^(r>>2))&3
    const int sq8 = (quad ^ ((lm ^ (lm >> 2)) & 3)) * 8;

    floatx4 acc[8][4] = {};

    auto stage = [&](int buf, int k0) {
        #pragma unroll
        for (int s4 = 0; s4 < 4; ++s4) {        // A: 1024 chunks / 256 thr
            const int c = s4 * 256 + tid;
            const int r = c >> 2, q = c & 3;
            const int col = (q ^ ((r ^ (r >> 2)) & 3)) * 8;
            GLOAD_LDS16(A_g + (size_t)(row0 + r) * K + k0 + col, &Ah[buf][c * 8]);
        }
        #pragma unroll
        for (int s2 = 0; s2 < 2; ++s2) {        // B: 512 chunks / 256 thr
            const int c = s2 * 256 + tid;
            const int r = c >> 2, q = c & 3;
            const int col = (q ^ ((r ^ (r >> 2)) & 3)) * 8;
            GLOAD_LDS16(B_g + (size_t)(col0 + r) * K + k0 + col, &Bh[buf][c * 8]);
        }
    };

    // prologue: tiles 0 and 1 in flight (12 loads)
    stage(0, 0);
    stage(1, BK);

    int cur = 0;
    for (int kt = 0; kt < NI; ++kt) {
        if (kt < NI - 1) { WAITVM6; } else { WAITVM0; }   // counted, never drain mid-loop
        __builtin_amdgcn_s_barrier();
        asm volatile("" ::: "memory");

        if (kt + 2 < NI) {
            int stg = cur + 2; if (stg >= 3) stg -= 3;
            stage(stg, (kt + 2) * BK);
        }

        short8 af[8];
        #pragma unroll
        for (int i = 0; i < 8; ++i)
            af[i] = *(const short8*)&Ah[cur][(wy * 128 + i * 16 + lm) * BK + sq8];

        __builtin_amdgcn_s_setprio(1);
        #pragma unroll
        for (int j = 0; j < 4; ++j) {
            short8 bf = *(const short8*)&Bh[cur][(wx * 64 + j * 16 + lm) * BK + sq8];
            #pragma unroll
            for (int i = 0; i < 8; ++i)
                acc[i][j] = __builtin_amdgcn_mfma_f32_16x16x32_bf16(af[i], bf, acc[i][j], 0, 0, 0);
        }
        __builtin_amdgcn_s_setprio(0);

        cur = (cur == 2) ? 0 : cur + 1;
    }

    // ---- coalesced epilogue: per-wave LDS bounce (2KB/wave region) ----
    float bvj[4];
    #pragma unroll
    for (int j = 0; j < 4; ++j) bvj[j] = bias[col0 + wx * 64 + j * 16 + lm];

    unsigned short* wbuf = &Ah[0][wave * 1024];   // 16 rows x 64 cols
    #pragma unroll
    for (int i = 0; i < 8; ++i) {
        #pragma unroll
        for (int j = 0; j < 4; ++j) {
            #pragma unroll
            for (int r = 0; r < 4; ++r)
                wbuf[(quad * 4 + r) * 64 + j * 16 + lm] = f32_to_bf16_rn(acc[i][j][r] + bvj[j]);
        }
        asm volatile("s_waitcnt lgkmcnt(0)" ::: "memory");  // cross-lane RAW
        #pragma unroll
        for (int p = 0; p < 2; ++p) {
            const int lrow  = p * 8 + (lane >> 3);
            const int lcol8 = (lane & 7) * 8;
            short8 v = lds_ld8(&wbuf[lrow * 64 + lcol8]);
            *(short8*)(Cb + (size_t)(row0 + wy * 128 + i * 16 + lrow) * N +
                       col0 + wx * 64 + lcol8) = v;
        }
        asm volatile("s_waitcnt lgkmcnt(0)" ::: "memory");  // WAR before next i
    }
}

// ---------------------------------------------------------------------------
// bf16 GEMM (proj): out[M,N] = AO @ B^T + bias, fp32 out.
// AO is HEAD-MAJOR bf16 [NH][M][HD]; staging translates k -> (head, off).
// Same counted-vmcnt triple-buffered structure as gemm_qkv.
// ---------------------------------------------------------------------------
__global__ __launch_bounds__(256, 2)
void gemm_proj(const unsigned short* __restrict__ AO_g,
               const unsigned short* __restrict__ B_g,
               const float* __restrict__ bias,
               float* __restrict__ C,
               int M, int N, int K)
{
    constexpr int BM = 256, BN = 128, BK = 32;
    __shared__ __align__(16) unsigned short Ah[3][BM * BK];
    __shared__ __align__(16) unsigned short Bh[3][BN * BK];

    const int tid  = threadIdx.x;
    const int wave = tid >> 6;
    const int lane = tid & 63;
    const int lm   = lane & 15;
    const int quad = lane >> 4;
    const int wy   = wave >> 1, wx = wave & 1;

    const int nby = M / BM;                     // 32
    const int nwg = (N / BN) * nby;             // 192
    const int sid = (blockIdx.x & 7) * (nwg >> 3) + (blockIdx.x >> 3);
    const int by  = sid & (nby - 1);
    const int bx  = sid / nby;
    const int row0 = by * BM, col0 = bx * BN;
    const int NI  = K / BK;

    const int sq8 = (quad ^ ((lm ^ (lm >> 2)) & 3)) * 8;

    floatx4 acc[8][4] = {};

    auto stage = [&](int buf, int k0) {
        const int head = k0 >> 6;               // HD = 64, BK=32 stays in-head
        const int offb = k0 & 63;
        #pragma unroll
        for (int s4 = 0; s4 < 4; ++s4) {
            const int c = s4 * 256 + tid;
            const int r = c >> 2, q = c & 3;
            const int col = (q ^ ((r ^ (r >> 2)) & 3)) * 8;
            GLOAD_LDS16(AO_g + (size_t)head * (Mrows * HD) +
                        (size_t)(row0 + r) * HD + offb + col, &Ah[buf][c * 8]);
        }
        #pragma unroll
        for (int s2 = 0; s2 < 2; ++s2) {
            const int c = s2 * 256 + tid;
            const int r = c >> 2, q = c & 3;
            const int col = (q ^ ((r ^ (r >> 2)) & 3)) * 8;
            GLOAD_LDS16(B_g + (size_t)(col0 + r) * K + k0 + col, &Bh[buf][c * 8]);
        }
    };

    stage(0, 0);
    stage(1, BK);

    int cur = 0;
    for (int kt = 0; kt < NI; ++kt) {
        if (kt < NI - 1) { WAITVM6; } else { WAITVM0; }
        __builtin_amdgcn_s_barrier();
        asm volatile("" ::: "memory");

        if (kt + 2 < NI) {
            int stg = cur + 2; if (stg >= 3) stg -= 3;
            stage(stg, (kt + 2) * BK);
        }

        short8 af[8];
        #pragma unroll
        for (int i = 0; i < 8; ++i)
            af[i] = *(const short8*)&Ah[cur][(wy * 128 + i * 16 + lm) * BK + sq8];

        __builtin_amdgcn_s_setprio(1);
        #pragma unroll
        for (int j = 0; j < 4; ++j) {
            short8 bf = *(const short8*)&Bh[cur][(wx * 64 + j * 16 + lm) * BK + sq8];
            #pragma unroll
            for (int i = 0; i < 8; ++i)
                acc[i][j] = __builtin_amdgcn_mfma_f32_16x16x32_bf16(af[i], bf, acc[i][j], 0, 0, 0);
        }
        __builtin_amdgcn_s_setprio(0);

        cur = (cur == 2) ? 0 : cur + 1;
    }

    #pragma unroll
    for (int j = 0; j < 4; ++j) {
        const int col = col0 + wx * 64 + j * 16 + lm;
        const float bv = bias[col];
        #pragma unroll
        for (int i = 0; i < 8; ++i) {
            const int rowb = row0 + wy * 128 + i * 16 + quad * 4;
            #pragma unroll
            for (int r = 0; r < 4; ++r)
                C[(size_t)(rowb + r) * N + col] = acc[i][j][r] + bv;
        }
    }
}

// ---------------------------------------------------------------------------
// Pure-bf16 MFMA flash attention, DOUBLE-BUFFERED K/V: one barrier per tile.
// (unchanged from R9 — next round's target once GEMM counters confirm)
// ---------------------------------------------------------------------------
__global__ __launch_bounds__(256, 2)
void attn_bf16(const unsigned short* __restrict__ qkv,
               const int* __restrict__ mask,
               unsigned short* __restrict__ outh)
{
    constexpr int LDW = 68;
    constexpr int NT  = Tseq / 64;     // 16 K-tiles
    __shared__ __align__(16) unsigned short Kh[2][64 * LDW];
    __shared__ __align__(16) unsigned short Vh[2][64 * LDW];   // V^T [d][k]
    __shared__ __align__(16) unsigned short Ph[128 * LDW];
    __shared__ float maskadd[2][64];

    const int tid  = threadIdx.x;
    const int wave = tid >> 6;
    const int lane = tid & 63;
    const int lm   = lane & 15;
    const int quad = lane >> 4;
    const int idx  = blockIdx.x;
    const int bh   = idx % (Bsz * NH);
    const int qb   = idx / (Bsz * NH);
    const int b    = bh / NH;
    const int h    = bh % NH;
    const int q0   = qb * 128;
    const float scale = 0.125f;        // 1/sqrt(64)

    // Q fragments (B-layout: n=lm, k=quad*8+j) straight from global
    short8 qf[2][2];
    #pragma unroll
    for (int mt = 0; mt < 2; ++mt) {
        const size_t qrow = (size_t)(b * Tseq + q0 + wave * 32 + mt * 16 + lm) * C3 + h * HD;
        #pragma unroll
        for (int kf = 0; kf < 2; ++kf)
            qf[mt][kf] = *(const short8*)(qkv + qrow + kf * 32 + quad * 8);
    }

    const int sr0 = (tid & 31) * 2;    // k-row pair
    const int sc  = (tid >> 5) * 8;    // 8 dims

    short8 kh0, kh1, vh0, vh1;
    float  mreg = 0.f;

    // --- prefetch + store tile 0 into buf 0 ---
    {
        const size_t g0 = (size_t)(b * Tseq + sr0) * C3 + Cdim + h * HD + sc;
        kh0 = *(const short8*)(qkv + g0);
        kh1 = *(const short8*)(qkv + g0 + C3);
        vh0 = *(const short8*)(qkv + g0 + Cdim);
        vh1 = *(const short8*)(qkv + g0 + Cdim + C3);
        if (tid < 64) mreg = (mask[b * Tseq + tid] == 0) ? -1e30f : 0.0f;
        lds_st8(&Kh[0][sr0 * LDW + sc], kh0);
        lds_st8(&Kh[0][(sr0 + 1) * LDW + sc], kh1);
        #pragma unroll
        for (int i = 0; i < 8; ++i) {
            unsigned int pv = (unsigned int)(unsigned short)vh0[i] |
                              ((unsigned int)(unsigned short)vh1[i] << 16);
            *(unsigned int*)&Vh[0][(sc + i) * LDW + sr0] = pv;
        }
        if (tid < 64) maskadd[0][tid] = mreg;
    }
    __syncthreads();

    floatx4 O[2][4] = {};              // [m][d-tile]; lane: q=lm, d=quad*4+r
    float lsum[2] = {0.f, 0.f};
    float madd[4][4];

    for (int kt = 0; kt < NT; ++kt) {
        const int cur = kt & 1;
        const int nxt = cur ^ 1;
        const unsigned short* Khc = Kh[cur];
        const unsigned short* Vhc = Vh[cur];

        // ---- issue prefetch for tile kt+1 early (latency behind compute) ----
        if (kt + 1 < NT) {
            const size_t g0 = (size_t)(b * Tseq + (kt + 1) * 64 + sr0) * C3 + Cdim + h * HD + sc;
            kh0 = *(const short8*)(qkv + g0);
            kh1 = *(const short8*)(qkv + g0 + C3);
            vh0 = *(const short8*)(qkv + g0 + Cdim);
            vh1 = *(const short8*)(qkv + g0 + Cdim + C3);
            if (tid < 64) mreg = (mask[b * Tseq + (kt + 1) * 64 + tid] == 0) ? -1e30f : 0.0f;
        }

        // ---- S^T = K Q^T : D[k][q], lane: q=lm, k=quad*4+r ----
        floatx4 S[2][4] = {};
        #pragma unroll
        for (int kf = 0; kf < 2; ++kf) {
            short8 kh[4];
            #pragma unroll
            for (int nt = 0; nt < 4; ++nt)
                kh[nt] = lds_ld8(&Khc[(nt * 16 + lm) * LDW + kf * 32 + quad * 8]);
            #pragma unroll
            for (int mt = 0; mt < 2; ++mt)
                #pragma unroll
                for (int nt = 0; nt < 4; ++nt)
                    S[mt][nt] = __builtin_amdgcn_mfma_f32_16x16x32_bf16(kh[nt], qf[mt][kf], S[mt][nt], 0, 0, 0);
        }
        #pragma unroll
        for (int nt = 0; nt < 4; ++nt)
            #pragma unroll
            for (int r = 0; r < 4; ++r)
                madd[nt][r] = maskadd[cur][nt * 16 + quad * 4 + r];

        // ---- softmax numerator (no max shift), packed P store ----
        #pragma unroll
        for (int mt = 0; mt < 2; ++mt) {
            const int prow = (wave * 32 + mt * 16 + lm) * LDW;
            #pragma unroll
            for (int nt = 0; nt < 4; ++nt) {
                ushort4 pk;
                unsigned short* pp = &pk.x;
                #pragma unroll
                for (int r = 0; r < 4; ++r) {
                    float p = __expf(S[mt][nt][r] * scale + madd[nt][r]);
                    lsum[mt] += p;
                    pp[r] = f32_to_bf16_rn(p);
                }
                *(ushort4*)&Ph[prow + nt * 16 + quad * 4] = pk;
            }
        }

        // ---- O^T += V^T P^T (P wave-private: no barrier) ----
        #pragma unroll
        for (int kf = 0; kf < 2; ++kf) {
            short8 pf[2];
            #pragma unroll
            for (int mt = 0; mt < 2; ++mt)
                pf[mt] = lds_ld8(&Ph[(wave * 32 + mt * 16 + lm) * LDW + kf * 32 + quad * 8]);
            #pragma unroll
            for (int dt = 0; dt < 4; ++dt) {
                short8 vh = lds_ld8(&Vhc[(dt * 16 + lm) * LDW + kf * 32 + quad * 8]);
                #pragma unroll
                for (int mt = 0; mt < 2; ++mt)
                    O[mt][dt] = __builtin_amdgcn_mfma_f32_16x16x32_bf16(vh, pf[mt], O[mt][dt], 0, 0, 0);
            }
        }

        // ---- store prefetched tile into the other buffer ----
        if (kt + 1 < NT) {
            lds_st8(&Kh[nxt][sr0 * LDW + sc], kh0);
            lds_st8(&Kh[nxt][(sr0 + 1) * LDW + sc], kh1);
            #pragma unroll
            for (int i = 0; i < 8; ++i) {
                unsigned int pv = (unsigned int)(unsigned short)vh0[i] |
                                  ((unsigned int)(unsigned short)vh1[i] << 16);
                *(unsigned int*)&Vh[nxt][(sc + i) * LDW + sr0] = pv;
            }
            if (tid < 64) maskadd[nxt][tid] = mreg;
        }
        __syncthreads();               // single barrier: orders store->read
    }

    // ---- final l reduction across quads, normalize, head-major write ----
    #pragma unroll
    for (int mt = 0; mt < 2; ++mt) {
        lsum[mt] += __shfl_xor(lsum[mt], 16);
        lsum[mt] += __shfl_xor(lsum[mt], 32);
        const float inv_l = 1.0f / lsum[mt];
        const size_t row = (size_t)h * (Mrows * HD) +
                           (size_t)(b * Tseq + q0 + wave * 32 + mt * 16 + lm) * HD;
        #pragma unroll
        for (int dt = 0; dt < 4; ++dt) {
            ushort4 hv;
            unsigned short* hp = &hv.x;
            #pragma unroll
            for (int r = 0; r < 4; ++r)
                hp[r] = f32_to_bf16_rn(O[mt][dt][r] * inv_l);
            *(ushort4*)(outh + row + dt * 16 + quad * 4) = hv;
        }
    }
}

// ---------------------------------------------------------------------------
extern "C" void kernel_launch(void* const* d_in, const int* in_sizes, int n_in,
                              void* d_out, int out_size, void* d_ws, size_t ws_size,
                              hipStream_t stream)
{
    const float* x      = (const float*)d_in[0];
    const int*   mask   = (const int*)  d_in[1];
    const float* W_attn = (const float*)d_in[2];
    const float* b_attn = (const float*)d_in[3];
    const float* W_proj = (const float*)d_in[4];
    const float* b_proj = (const float*)d_in[5];
    float* out = (float*)d_out;

    // workspace (~55 MB)
    unsigned short* xh    = (unsigned short*)d_ws;               // [8192][768]
    unsigned short* wat_h = xh    + (size_t)Mrows * Cdim;        // W_attn^T
    unsigned short* wpt_h = wat_h + (size_t)C3 * Cdim;           // W_proj^T
    unsigned short* qkvh  = wpt_h + (size_t)Cdim * Cdim;         // [8192][2304]
    unsigned short* aoh   = xh;    // reuse: xh dead after gemm1; [12][8192][64]

    dim3 blk(256);

    to_bf16<<<dim3(Mrows * Cdim / 4 / 256), blk, 0, stream>>>(x, xh, Mrows * Cdim / 4);
    transpose_bf16<<<dim3(C3 / 32, Cdim / 32), blk, 0, stream>>>(W_attn, wat_h, Cdim, C3);
    transpose_bf16<<<dim3(Cdim / 32, Cdim / 32), blk, 0, stream>>>(W_proj, wpt_h, Cdim, Cdim);

    // qkv = x @ W_attn + b_attn  (bf16 out, coalesced epilogue)
    // grid: (2304/128) * (8192/256) = 18 * 32 = 576 blocks (%8==0 for T1)
    gemm_qkv<<<dim3((C3 / 128) * (Mrows / 256)), blk, 0, stream>>>(
        xh, wat_h, b_attn, qkvh, Mrows, C3, Cdim);

    // attention -> head-major bf16
    attn_bf16<<<dim3((Tseq / 128) * Bsz * NH), blk, 0, stream>>>(qkvh, mask, aoh);

    // out = attnout @ W_proj + b_proj (fp32 out)
    // grid: (768/128) * (8192/256) = 6 * 32 = 192 blocks (%8==0 for T1)
    gemm_proj<<<dim3((Cdim / 128) * (Mrows / 256)), blk, 0, stream>>>(
        aoh, wpt_h, b_proj, out, Mrows, Cdim, Cdim);
}

// Round 2
// 207.301 us; speedup vs baseline: 1.1021x; 1.1021x over previous
//
#include <hip/hip_runtime.h>
#include <math.h>

// Problem constants (B=8, T=1024, C=768, 12 heads, hd=64)
constexpr int Bsz  = 8;
constexpr int Tseq = 1024;
constexpr int Cdim = 768;
constexpr int NH   = 12;
constexpr int HD   = 64;
constexpr int Mrows = Bsz * Tseq;   // 8192
constexpr int C3    = 3 * Cdim;     // 2304

using short8  = __attribute__((ext_vector_type(8))) short;
using s4v     = __attribute__((ext_vector_type(4))) short;
using floatx4 = __attribute__((ext_vector_type(4))) float;

__device__ __forceinline__ unsigned short f32_to_bf16_rn(float f) {
    unsigned int u = __float_as_uint(f);
    unsigned int r = u + 0x7FFFu + ((u >> 16) & 1u);
    return (unsigned short)(r >> 16);
}
__device__ __forceinline__ short8 lds_ld8(const unsigned short* p) {
    s4v a = *(const s4v*)p;
    s4v b = *(const s4v*)(p + 4);
    return __builtin_shufflevector(a, b, 0, 1, 2, 3, 4, 5, 6, 7);
}
__device__ __forceinline__ void lds_st8(unsigned short* p, short8 v) {
    *(s4v*)p       = __builtin_shufflevector(v, v, 0, 1, 2, 3);
    *(s4v*)(p + 4) = __builtin_shufflevector(v, v, 4, 5, 6, 7);
}

#define GLOAD_LDS16(g, l) __builtin_amdgcn_global_load_lds(                    \
    (const __attribute__((address_space(1))) void*)(g),                        \
    (__attribute__((address_space(3))) void*)(l), 16, 0, 0)

#define WAITVM0 asm volatile("s_waitcnt vmcnt(0)" ::: "memory")

// ---------------------------------------------------------------------------
// fp32 -> bf16 (round-to-nearest), vectorized.
// ---------------------------------------------------------------------------
__global__ __launch_bounds__(256)
void to_bf16(const float* __restrict__ in, unsigned short* __restrict__ out, int n4)
{
    int t = blockIdx.x * blockDim.x + threadIdx.x;
    if (t >= n4) return;
    float4 v = ((const float4*)in)[t];
    ushort4 o;
    o.x = f32_to_bf16_rn(v.x);
    o.y = f32_to_bf16_rn(v.y);
    o.z = f32_to_bf16_rn(v.z);
    o.w = f32_to_bf16_rn(v.w);
    ((ushort4*)out)[t] = o;
}

// ---------------------------------------------------------------------------
// Transpose fp32 [K][N] -> bf16 [N][K].
// ---------------------------------------------------------------------------
__global__ __launch_bounds__(256)
void transpose_bf16(const float* __restrict__ in, unsigned short* __restrict__ out,
                    int K, int N)
{
    __shared__ float tile[32][33];
    const int k0 = blockIdx.y * 32, n0 = blockIdx.x * 32;
    const int tx = threadIdx.x & 31, ty = threadIdx.x >> 5;
    #pragma unroll
    for (int r = ty; r < 32; r += 8)
        tile[r][tx] = in[(size_t)(k0 + r) * N + n0 + tx];
    __syncthreads();
    #pragma unroll
    for (int r = ty; r < 32; r += 8)
        out[(size_t)(n0 + r) * K + k0 + tx] = f32_to_bf16_rn(tile[tx][r]);
}

// ---------------------------------------------------------------------------
// bf16 GEMM (qkv): C[M,N] = A[M,K] @ B^T + bias, bf16 out.
//
// R11: fine-phase counted-vmcnt pipeline.
//   MH=2: BM=256 x BN=256 (big blocks);  MH=1: BM=128 x BN=256 (tail blocks).
//   BK=32, 3 LDS buffers (96 KB) so staging runs 2 tiles ahead and the
//   per-tile wait is vmcnt(MH+2): retires tile t+1's loads, keeps t+2's in
//   flight.  vmcnt(0) only at tile NI-2 (last staged tile must land).
//   2 phases per K-tile, each: {ds_read frags ; 2 x global_load_lds ;
//   raw s_barrier ; setprio(1) ; 16 MFMA ; setprio(0) ; barrier} — the
//   m201-template granularity (16 MFMA/phase, 2 gload/phase).
//   Source-side XOR swizzle (chunk q of row r at q ^ ((r^(r>>2))&3)) on the
//   staged global address; read side folds to a per-lane constant.
//   Epilogue LDS bounce padded to 68-col stride (136 B) — kills the 8-way
//   write conflicts that were ~3.2M of the 4.1M SQ_LDS_BANK_CONFLICT.
// ---------------------------------------------------------------------------
template<int MH>
__device__ __forceinline__ void qkv_body(
    const unsigned short* __restrict__ A_g,
    const unsigned short* __restrict__ B_g,
    const float* __restrict__ bias,
    unsigned short* __restrict__ Cb,
    const int row0, const int col0, const int K, const int N,
    unsigned short* lds)
{
    constexpr int BK   = 32;
    constexpr int BUFS = 16384;          // ushorts per buffer (A 8192 + B 8192)

    const int tid  = threadIdx.x;        // 0..511
    const int wave = tid >> 6;           // 0..7
    const int lane = tid & 63;
    const int lm   = lane & 15;
    const int quad = lane >> 4;
    const int wy   = wave >> 2;          // 0..1  (M split)
    const int wx   = wave & 3;           // 0..3  (N split)
    const int NI   = K / BK;             // 24
    const int sq8  = (quad ^ ((lm ^ (lm >> 2)) & 3)) * 8;
    const int sr   = tid >> 2;           // staging row within 128-row half
    const int sq   = tid & 3;            // staging chunk

    floatx4 acc[4 * MH][4] = {};

    auto stageA = [&](int buf, int k0, int h) {
        const int r  = h * 128 + sr;
        const int gc = k0 + ((sq ^ ((r ^ (r >> 2)) & 3)) << 3);
        GLOAD_LDS16(A_g + (size_t)(row0 + r) * K + gc,
                    lds + buf * BUFS + r * 32 + sq * 8);
    };
    auto stageB = [&](int buf, int k0, int h) {
        const int r  = h * 128 + sr;
        const int gc = k0 + ((sq ^ ((r ^ (r >> 2)) & 3)) << 3);
        GLOAD_LDS16(B_g + (size_t)(col0 + r) * K + gc,
                    lds + buf * BUFS + 8192 + r * 32 + sq * 8);
    };

    // prologue: tile 0 -> buf0, tile 1 -> buf1  (2*(MH+2) loads in flight)
    #pragma unroll
    for (int h = 0; h < MH; ++h) stageA(0, 0, h);
    stageB(0, 0, 0); stageB(0, 0, 1);
    #pragma unroll
    for (int h = 0; h < MH; ++h) stageA(1, BK, h);
    stageB(1, BK, 0); stageB(1, BK, 1);
    if constexpr (MH == 2) asm volatile("s_waitcnt vmcnt(4)" ::: "memory");
    else                   asm volatile("s_waitcnt vmcnt(3)" ::: "memory");
    __builtin_amdgcn_s_barrier();

    short8 af[2 * MH], bf[4];
    int cur = 0;
    for (int kt = 0; kt < NI; ++kt) {
        const unsigned short* bufA = lds + cur * BUFS;
        const unsigned short* bufB = bufA + 8192;
        const int  stg  = (cur + 2 >= 3) ? cur - 1 : cur + 2;
        const int  k2   = (kt + 2) * BK;
        const bool doSt = (kt + 2 < NI);

        // ---- phase 0: m-half 0, all N ----
        #pragma unroll
        for (int u = 0; u < 2 * MH; ++u)
            af[u] = *(const short8*)(bufA + (wy * (64 * MH) + u * 16 + lm) * 32 + sq8);
        #pragma unroll
        for (int j = 0; j < 4; ++j)
            bf[j] = *(const short8*)(bufB + (wx * 64 + j * 16 + lm) * 32 + sq8);
        if (doSt) {
            stageA(stg, k2, 0);
            if constexpr (MH == 2) stageA(stg, k2, 1); else stageB(stg, k2, 0);
        }
        __builtin_amdgcn_s_barrier();
        __builtin_amdgcn_s_setprio(1);
        #pragma unroll
        for (int u = 0; u < 2 * MH; ++u)
            #pragma unroll
            for (int j = 0; j < 4; ++j)
                acc[u][j] = __builtin_amdgcn_mfma_f32_16x16x32_bf16(af[u], bf[j], acc[u][j], 0, 0, 0);
        __builtin_amdgcn_s_setprio(0);
        __builtin_amdgcn_s_barrier();

        // ---- phase 1: m-half 1, all N (bf reused) ----
        #pragma unroll
        for (int u = 0; u < 2 * MH; ++u)
            af[u] = *(const short8*)(bufA + (wy * (64 * MH) + (2 * MH + u) * 16 + lm) * 32 + sq8);
        if (doSt) {
            if constexpr (MH == 2) { stageB(stg, k2, 0); stageB(stg, k2, 1); }
            else                   stageB(stg, k2, 1);
        }
        __builtin_amdgcn_s_barrier();
        __builtin_amdgcn_s_setprio(1);
        #pragma unroll
        for (int u = 0; u < 2 * MH; ++u)
            #pragma unroll
            for (int j = 0; j < 4; ++j)
                acc[2 * MH + u][j] = __builtin_amdgcn_mfma_f32_16x16x32_bf16(af[u], bf[j], acc[2 * MH + u][j], 0, 0, 0);
        __builtin_amdgcn_s_setprio(0);
        // counted wait: retire tile kt+1's loads, keep kt+2's in flight.
        if (kt == NI - 2) { WAITVM0; }
        else if (kt < NI - 2) {
            if constexpr (MH == 2) asm volatile("s_waitcnt vmcnt(4)" ::: "memory");
            else                   asm volatile("s_waitcnt vmcnt(3)" ::: "memory");
        }
        __builtin_amdgcn_s_barrier();

        cur = (cur == 2) ? 0 : cur + 1;
    }
    asm volatile("" ::: "memory");

    // ---- coalesced epilogue: per-wave LDS bounce, PADDED stride 68 ----
    // wbuf lives in buf[NI%3] = buf0, which no wave reads during the last
    // tile (last tile reads buf[(NI-1)%3]); regions are wave-private.
    unsigned short* wbuf = lds + (NI % 3) * BUFS + wave * 1088;   // 16 x 68
    float bvj[4];
    #pragma unroll
    for (int j = 0; j < 4; ++j) bvj[j] = bias[col0 + wx * 64 + j * 16 + lm];
    #pragma unroll
    for (int i = 0; i < 4 * MH; ++i) {
        #pragma unroll
        for (int j = 0; j < 4; ++j) {
            #pragma unroll
            for (int r = 0; r < 4; ++r)
                wbuf[(quad * 4 + r) * 68 + j * 16 + lm] = f32_to_bf16_rn(acc[i][j][r] + bvj[j]);
        }
        asm volatile("s_waitcnt lgkmcnt(0)" ::: "memory");  // cross-lane RAW
        #pragma unroll
        for (int p = 0; p < 2; ++p) {
            const int lrow  = p * 8 + (lane >> 3);
            const int lcol8 = (lane & 7) * 8;
            short8 v = lds_ld8(&wbuf[lrow * 68 + lcol8]);
            *(short8*)(Cb + (size_t)(row0 + wy * (64 * MH) + i * 16 + lrow) * N +
                       col0 + wx * 64 + lcol8) = v;
        }
        asm volatile("s_waitcnt lgkmcnt(0)" ::: "memory");  // WAR before next i
    }
}

__global__ __launch_bounds__(512, 1)
void gemm_qkv8p(const unsigned short* __restrict__ A_g,
                const unsigned short* __restrict__ B_g,
                const float* __restrict__ bias,
                unsigned short* __restrict__ Cb)
{
    __shared__ __align__(16) unsigned short lds[3 * 16384];   // 96 KB
    const int bid = blockIdx.x;
    if (bid < 256) {
        // big tiles: 32 row-tiles x 8 col-tiles (cols 0..2047), XCD-swizzled
        const int sid = (bid & 7) * 32 + (bid >> 3);
        qkv_body<2>(A_g, B_g, bias, Cb,
                    (sid >> 3) * 256, (sid & 7) * 256, Cdim, C3, lds);
    } else {
        // tail strip: cols 2048..2303, 64 row-tiles of 128 (dispatched last,
        // backfills the CUs as big blocks finish -> makespan ~ T + T/2)
        const int t   = bid - 256;
        const int sid = (t & 7) * 8 + (t >> 3);
        qkv_body<1>(A_g, B_g, bias, Cb, sid * 128, 2048, Cdim, C3, lds);
    }
}

// ---------------------------------------------------------------------------
// bf16 GEMM (proj): out[M,N] = AO @ B^T + bias, fp32 out.  (R9 known-good)
// AO is HEAD-MAJOR bf16 [NH][M][HD]; staging translates k -> (head, off).
// Double-buffered single-barrier K-loop, 128x128 tile, 4 waves.
// ---------------------------------------------------------------------------
__global__ __launch_bounds__(256)
void gemm_proj(const unsigned short* __restrict__ AO_g,
               const unsigned short* __restrict__ B_g,
               const float* __restrict__ bias,
               float* __restrict__ C,
               int M, int N, int K)
{
    __shared__ __align__(16) unsigned short Ah[2][128 * 32];
    __shared__ __align__(16) unsigned short Bh[2][128 * 32];

    const int tid  = threadIdx.x;
    const int wave = tid >> 6;
    const int lane = tid & 63;
    const int lm   = lane & 15;
    const int quad = lane >> 4;
    const int wy   = wave >> 1, wx = wave & 1;
    const int row0 = blockIdx.y * 128;
    const int col0 = blockIdx.x * 128;

    const int sr  = lane >> 2;
    const int skp = (lane & 3) * 8;
    const int NI  = K / 32;

    floatx4 acc[4][4] = {};

    {
        const int head0 = skp >> 6, off0 = skp & 63;
        #pragma unroll
        for (int s = 0; s < 2; ++s) {
            const int r = (wave * 2 + s) * 16 + sr;
            GLOAD_LDS16(AO_g + (size_t)head0 * (Mrows * HD) + (size_t)(row0 + r) * HD + off0,
                        &Ah[0][r * 32 + skp]);
            GLOAD_LDS16(B_g + (size_t)(col0 + r) * K + skp, &Bh[0][r * 32 + skp]);
        }
    }
    __syncthreads();

    for (int kt = 0; kt < NI; ++kt) {
        const int cur = kt & 1, nxt = cur ^ 1;

        if (kt + 1 < NI) {
            const int k0   = (kt + 1) * 32;
            const int kk   = k0 + skp;
            const int head = kk >> 6;          // HD = 64
            const int off  = kk & 63;
            #pragma unroll
            for (int s = 0; s < 2; ++s) {
                const int r = (wave * 2 + s) * 16 + sr;
                GLOAD_LDS16(AO_g + (size_t)head * (Mrows * HD) + (size_t)(row0 + r) * HD + off,
                            &Ah[nxt][r * 32 + skp]);
                GLOAD_LDS16(B_g + (size_t)(col0 + r) * K + k0 + skp, &Bh[nxt][r * 32 + skp]);
            }
        }

        short8 af[4];
        #pragma unroll
        for (int i = 0; i < 4; ++i)
            af[i] = *(const short8*)&Ah[cur][(wy * 64 + i * 16 + lm) * 32 + quad * 8];
        #pragma unroll
        for (int j = 0; j < 4; ++j) {
            short8 bf = *(const short8*)&Bh[cur][(wx * 64 + j * 16 + lm) * 32 + quad * 8];
            #pragma unroll
            for (int i = 0; i < 4; ++i)
                acc[i][j] = __builtin_amdgcn_mfma_f32_16x16x32_bf16(af[i], bf, acc[i][j], 0, 0, 0);
        }

        __syncthreads();               // single barrier: orders stage->read
    }

    #pragma unroll
    for (int j = 0; j < 4; ++j) {
        const int col = col0 + wx * 64 + j * 16 + lm;
        const float bv = bias[col];
        #pragma unroll
        for (int i = 0; i < 4; ++i) {
            const int rowb = row0 + wy * 64 + i * 16 + quad * 4;
            #pragma unroll
            for (int r = 0; r < 4; ++r)
                C[(size_t)(rowb + r) * N + col] = acc[i][j][r] + bv;
        }
    }
}

// ---------------------------------------------------------------------------
// Pure-bf16 MFMA flash attention, DOUBLE-BUFFERED K/V: one barrier per tile.
// (unchanged R9)
// ---------------------------------------------------------------------------
__global__ __launch_bounds__(256, 2)
void attn_bf16(const unsigned short* __restrict__ qkv,
               const int* __restrict__ mask,
               unsigned short* __restrict__ outh)
{
    constexpr int LDW = 68;
    constexpr int NT  = Tseq / 64;     // 16 K-tiles
    __shared__ __align__(16) unsigned short Kh[2][64 * LDW];
    __shared__ __align__(16) unsigned short Vh[2][64 * LDW];   // V^T [d][k]
    __shared__ __align__(16) unsigned short Ph[128 * LDW];
    __shared__ float maskadd[2][64];

    const int tid  = threadIdx.x;
    const int wave = tid >> 6;
    const int lane = tid & 63;
    const int lm   = lane & 15;
    const int quad = lane >> 4;
    const int idx  = blockIdx.x;
    const int bh   = idx % (Bsz * NH);
    const int qb   = idx / (Bsz * NH);
    const int b    = bh / NH;
    const int h    = bh % NH;
    const int q0   = qb * 128;
    const float scale = 0.125f;        // 1/sqrt(64)

    short8 qf[2][2];
    #pragma unroll
    for (int mt = 0; mt < 2; ++mt) {
        const size_t qrow = (size_t)(b * Tseq + q0 + wave * 32 + mt * 16 + lm) * C3 + h * HD;
        #pragma unroll
        for (int kf = 0; kf < 2; ++kf)
            qf[mt][kf] = *(const short8*)(qkv + qrow + kf * 32 + quad * 8);
    }

    const int sr0 = (tid & 31) * 2;    // k-row pair
    const int sc  = (tid >> 5) * 8;    // 8 dims

    short8 kh0, kh1, vh0, vh1;
    float  mreg = 0.f;

    {
        const size_t g0 = (size_t)(b * Tseq + sr0) * C3 + Cdim + h * HD + sc;
        kh0 = *(const short8*)(qkv + g0);
        kh1 = *(const short8*)(qkv + g0 + C3);
        vh0 = *(const short8*)(qkv + g0 + Cdim);
        vh1 = *(const short8*)(qkv + g0 + Cdim + C3);
        if (tid < 64) mreg = (mask[b * Tseq + tid] == 0) ? -1e30f : 0.0f;
        lds_st8(&Kh[0][sr0 * LDW + sc], kh0);
        lds_st8(&Kh[0][(sr0 + 1) * LDW + sc], kh1);
        #pragma unroll
        for (int i = 0; i < 8; ++i) {
            unsigned int pv = (unsigned int)(unsigned short)vh0[i] |
                              ((unsigned int)(unsigned short)vh1[i] << 16);
            *(unsigned int*)&Vh[0][(sc + i) * LDW + sr0] = pv;
        }
        if (tid < 64) maskadd[0][tid] = mreg;
    }
    __syncthreads();

    floatx4 O[2][4] = {};              // [m][d-tile]; lane: q=lm, d=quad*4+r
    float lsum[2] = {0.f, 0.f};
    float madd[4][4];

    for (int kt = 0; kt < NT; ++kt) {
        const int cur = kt & 1;
        const int nxt = cur ^ 1;
        const unsigned short* Khc = Kh[cur];
        const unsigned short* Vhc = Vh[cur];

        if (kt + 1 < NT) {
            const size_t g0 = (size_t)(b * Tseq + (kt + 1) * 64 + sr0) * C3 + Cdim + h * HD + sc;
            kh0 = *(const short8*)(qkv + g0);
            kh1 = *(const short8*)(qkv + g0 + C3);
            vh0 = *(const short8*)(qkv + g0 + Cdim);
            vh1 = *(const short8*)(qkv + g0 + Cdim + C3);
            if (tid < 64) mreg = (mask[b * Tseq + (kt + 1) * 64 + tid] == 0) ? -1e30f : 0.0f;
        }

        // ---- S^T = K Q^T ----
        floatx4 S[2][4] = {};
        #pragma unroll
        for (int kf = 0; kf < 2; ++kf) {
            short8 kh[4];
            #pragma unroll
            for (int nt = 0; nt < 4; ++nt)
                kh[nt] = lds_ld8(&Khc[(nt * 16 + lm) * LDW + kf * 32 + quad * 8]);
            #pragma unroll
            for (int mt = 0; mt < 2; ++mt)
                #pragma unroll
                for (int nt = 0; nt < 4; ++nt)
                    S[mt][nt] = __builtin_amdgcn_mfma_f32_16x16x32_bf16(kh[nt], qf[mt][kf], S[mt][nt], 0, 0, 0);
        }
        #pragma unroll
        for (int nt = 0; nt < 4; ++nt)
            #pragma unroll
            for (int r = 0; r < 4; ++r)
                madd[nt][r] = maskadd[cur][nt * 16 + quad * 4 + r];

        // ---- softmax numerator (no max shift), packed P store ----
        #pragma unroll
        for (int mt = 0; mt < 2; ++mt) {
            const int prow = (wave * 32 + mt * 16 + lm) * LDW;
            #pragma unroll
            for (int nt = 0; nt < 4; ++nt) {
                ushort4 pk;
                unsigned short* pp = &pk.x;
                #pragma unroll
                for (int r = 0; r < 4; ++r) {
                    float p = __expf(S[mt][nt][r] * scale + madd[nt][r]);
                    lsum[mt] += p;
                    pp[r] = f32_to_bf16_rn(p);
                }
                *(ushort4*)&Ph[prow + nt * 16 + quad * 4] = pk;
            }
        }

        // ---- O^T += V^T P^T ----
        #pragma unroll
        for (int kf = 0; kf < 2; ++kf) {
            short8 pf[2];
            #pragma unroll
            for (int mt = 0; mt < 2; ++mt)
                pf[mt] = lds_ld8(&Ph[(wave * 32 + mt * 16 + lm) * LDW + kf * 32 + quad * 8]);
            #pragma unroll
            for (int dt = 0; dt < 4; ++dt) {
                short8 vh = lds_ld8(&Vhc[(dt * 16 + lm) * LDW + kf * 32 + quad * 8]);
                #pragma unroll
                for (int mt = 0; mt < 2; ++mt)
                    O[mt][dt] = __builtin_amdgcn_mfma_f32_16x16x32_bf16(vh, pf[mt], O[mt][dt], 0, 0, 0);
            }
        }

        if (kt + 1 < NT) {
            lds_st8(&Kh[nxt][sr0 * LDW + sc], kh0);
            lds_st8(&Kh[nxt][(sr0 + 1) * LDW + sc], kh1);
            #pragma unroll
            for (int i = 0; i < 8; ++i) {
                unsigned int pv = (unsigned int)(unsigned short)vh0[i] |
                                  ((unsigned int)(unsigned short)vh1[i] << 16);
                *(unsigned int*)&Vh[nxt][(sc + i) * LDW + sr0] = pv;
            }
            if (tid < 64) maskadd[nxt][tid] = mreg;
        }
        __syncthreads();
    }

    #pragma unroll
    for (int mt = 0; mt < 2; ++mt) {
        lsum[mt] += __shfl_xor(lsum[mt], 16);
        lsum[mt] += __shfl_xor(lsum[mt], 32);
        const float inv_l = 1.0f / lsum[mt];
        const size_t row = (size_t)h * (Mrows * HD) +
                           (size_t)(b * Tseq + q0 + wave * 32 + mt * 16 + lm) * HD;
        #pragma unroll
        for (int dt = 0; dt < 4; ++dt) {
            ushort4 hv;
            unsigned short* hp = &hv.x;
            #pragma unroll
            for (int r = 0; r < 4; ++r)
                hp[r] = f32_to_bf16_rn(O[mt][dt][r] * inv_l);
            *(ushort4*)(outh + row + dt * 16 + quad * 4) = hv;
        }
    }
}

// ---------------------------------------------------------------------------
extern "C" void kernel_launch(void* const* d_in, const int* in_sizes, int n_in,
                              void* d_out, int out_size, void* d_ws, size_t ws_size,
                              hipStream_t stream)
{
    const float* x      = (const float*)d_in[0];
    const int*   mask   = (const int*)  d_in[1];
    const float* W_attn = (const float*)d_in[2];
    const float* b_attn = (const float*)d_in[3];
    const float* W_proj = (const float*)d_in[4];
    const float* b_proj = (const float*)d_in[5];
    float* out = (float*)d_out;

    // workspace (~55 MB)
    unsigned short* xh    = (unsigned short*)d_ws;               // [8192][768]
    unsigned short* wat_h = xh    + (size_t)Mrows * Cdim;        // W_attn^T
    unsigned short* wpt_h = wat_h + (size_t)C3 * Cdim;           // W_proj^T
    unsigned short* qkvh  = wpt_h + (size_t)Cdim * Cdim;         // [8192][2304]
    unsigned short* aoh   = xh;    // reuse: xh dead after gemm1; [12][8192][64]

    dim3 blk(256);

    to_bf16<<<dim3(Mrows * Cdim / 4 / 256), blk, 0, stream>>>(x, xh, Mrows * Cdim / 4);
    transpose_bf16<<<dim3(C3 / 32, Cdim / 32), blk, 0, stream>>>(W_attn, wat_h, Cdim, C3);
    transpose_bf16<<<dim3(Cdim / 32, Cdim / 32), blk, 0, stream>>>(W_proj, wpt_h, Cdim, Cdim);

    // qkv = x @ W_attn + b_attn  (bf16 out)
    // 256 big blocks (256x256, cols 0..2047) + 64 tail blocks (128x256,
    // cols 2048..2303) dispatched last -> backfill, makespan ~ T + T/2.
    gemm_qkv8p<<<dim3(320), dim3(512), 0, stream>>>(xh, wat_h, b_attn, qkvh);

    // attention -> head-major bf16
    attn_bf16<<<dim3((Tseq / 128) * Bsz * NH), blk, 0, stream>>>(qkvh, mask, aoh);

    // out = attnout @ W_proj + b_proj (fp32 out)
    gemm_proj<<<dim3(Cdim / 128, Mrows / 128), blk, 0, stream>>>(
        aoh, wpt_h, b_proj, out, Mrows, Cdim, Cdim);
}

// Round 8
// 205.904 us; speedup vs baseline: 1.1096x; 1.0068x over previous
//
#include <hip/hip_runtime.h>
#include <hip/hip_bf16.h>
#include <math.h>

// Problem constants (B=8, T=1024, C=768, 12 heads, hd=64)
constexpr int Bsz  = 8;
constexpr int Tseq = 1024;
constexpr int Cdim = 768;
constexpr int NH   = 12;
constexpr int HD   = 64;
constexpr int Mrows = Bsz * Tseq;   // 8192
constexpr int C3    = 3 * Cdim;     // 2304

using short8  = __attribute__((ext_vector_type(8))) short;
using s4v     = __attribute__((ext_vector_type(4))) short;
using floatx4 = __attribute__((ext_vector_type(4))) float;

__device__ __forceinline__ unsigned short f32_to_bf16_rn(float f) {
    unsigned int u = __float_as_uint(f);
    unsigned int r = u + 0x7FFFu + ((u >> 16) & 1u);
    return (unsigned short)(r >> 16);
}
// Packed f32x2 -> bf16x2 via the VENDOR header (compiler owns instruction
// selection + operand order; struct layout pins .x to the LOW 16 bits).
// R12-R14 post-mortem: hand-written v_cvt_pk_bf16_f32 asm is the prime
// suspect for a pair-swap. Do NOT hand-write this instruction.
// NOTE: __builtin_bit_cast rejects __hip_bfloat162 (not trivially copyable
// in this ROCm's header) -> use 4-byte memcpy, same layout, free in codegen.
__device__ __forceinline__ unsigned pack_bf16x2_rn(float a, float b) {
    float2 f2; f2.x = a; f2.y = b;
    __hip_bfloat162 h = __float22bfloat162_rn(f2);
    unsigned r;
    __builtin_memcpy(&r, &h, sizeof(r));
    return r;
}
__device__ __forceinline__ short8 lds_ld8(const unsigned short* p) {
    s4v a = *(const s4v*)p;
    s4v b = *(const s4v*)(p + 4);
    return __builtin_shufflevector(a, b, 0, 1, 2, 3, 4, 5, 6, 7);
}
__device__ __forceinline__ void lds_st8(unsigned short* p, short8 v) {
    *(s4v*)p       = __builtin_shufflevector(v, v, 0, 1, 2, 3);
    *(s4v*)(p + 4) = __builtin_shufflevector(v, v, 4, 5, 6, 7);
}

#define GLOAD_LDS16(g, l) __builtin_amdgcn_global_load_lds(                    \
    (const __attribute__((address_space(1))) void*)(g),                        \
    (__attribute__((address_space(3))) void*)(l), 16, 0, 0)

#define WAITVM0 asm volatile("s_waitcnt vmcnt(0)" ::: "memory")
// Cross-lane LDS RAW fence (kept as insurance; R14 showed the Ph handoff was
// NOT the failure source, but the ordering guarantee is near-free).
#define LDS_XLANE_FENCE do {                                                   \
    asm volatile("s_waitcnt lgkmcnt(0)" ::: "memory");                         \
    __builtin_amdgcn_sched_barrier(0);                                         \
} while (0)

// ---------------------------------------------------------------------------
// fp32 -> bf16 (round-to-nearest), vectorized.
// ---------------------------------------------------------------------------
__global__ __launch_bounds__(256)
void to_bf16(const float* __restrict__ in, unsigned short* __restrict__ out, int n4)
{
    int t = blockIdx.x * blockDim.x + threadIdx.x;
    if (t >= n4) return;
    float4 v = ((const float4*)in)[t];
    ushort4 o;
    o.x = f32_to_bf16_rn(v.x);
    o.y = f32_to_bf16_rn(v.y);
    o.z = f32_to_bf16_rn(v.z);
    o.w = f32_to_bf16_rn(v.w);
    ((ushort4*)out)[t] = o;
}

// ---------------------------------------------------------------------------
// Transpose fp32 [K][N] -> bf16 [N][K].
// ---------------------------------------------------------------------------
__global__ __launch_bounds__(256)
void transpose_bf16(const float* __restrict__ in, unsigned short* __restrict__ out,
                    int K, int N)
{
    __shared__ float tile[32][33];
    const int k0 = blockIdx.y * 32, n0 = blockIdx.x * 32;
    const int tx = threadIdx.x & 31, ty = threadIdx.x >> 5;
    #pragma unroll
    for (int r = ty; r < 32; r += 8)
        tile[r][tx] = in[(size_t)(k0 + r) * N + n0 + tx];
    __syncthreads();
    #pragma unroll
    for (int r = ty; r < 32; r += 8)
        out[(size_t)(n0 + r) * K + k0 + tx] = f32_to_bf16_rn(tile[tx][r]);
}

// ---------------------------------------------------------------------------
// bf16 GEMM (qkv): C[M,N] = A[M,K] @ B^T + bias, bf16 out.
// R11 structure (verified): fine-phase counted-vmcnt pipeline, 3 LDS buffers,
// 2 phases/K-tile, src-side XOR swizzle, padded epilogue bounce, mixed
// 256x256 / 128x256 geometry for quantization.  UNCHANGED.
// ---------------------------------------------------------------------------
template<int MH>
__device__ __forceinline__ void qkv_body(
    const unsigned short* __restrict__ A_g,
    const unsigned short* __restrict__ B_g,
    const float* __restrict__ bias,
    unsigned short* __restrict__ Cb,
    const int row0, const int col0, const int K, const int N,
    unsigned short* lds)
{
    constexpr int BK   = 32;
    constexpr int BUFS = 16384;          // ushorts per buffer (A 8192 + B 8192)

    const int tid  = threadIdx.x;        // 0..511
    const int wave = tid >> 6;           // 0..7
    const int lane = tid & 63;
    const int lm   = lane & 15;
    const int quad = lane >> 4;
    const int wy   = wave >> 2;          // 0..1  (M split)
    const int wx   = wave & 3;           // 0..3  (N split)
    const int NI   = K / BK;             // 24
    const int sq8  = (quad ^ ((lm ^ (lm >> 2)) & 3)) * 8;
    const int sr   = tid >> 2;           // staging row within 128-row half
    const int sq   = tid & 3;            // staging chunk

    floatx4 acc[4 * MH][4] = {};

    auto stageA = [&](int buf, int k0, int h) {
        const int r  = h * 128 + sr;
        const int gc = k0 + ((sq ^ ((r ^ (r >> 2)) & 3)) << 3);
        GLOAD_LDS16(A_g + (size_t)(row0 + r) * K + gc,
                    lds + buf * BUFS + r * 32 + sq * 8);
    };
    auto stageB = [&](int buf, int k0, int h) {
        const int r  = h * 128 + sr;
        const int gc = k0 + ((sq ^ ((r ^ (r >> 2)) & 3)) << 3);
        GLOAD_LDS16(B_g + (size_t)(col0 + r) * K + gc,
                    lds + buf * BUFS + 8192 + r * 32 + sq * 8);
    };

    // prologue: tile 0 -> buf0, tile 1 -> buf1  (2*(MH+2) loads in flight)
    #pragma unroll
    for (int h = 0; h < MH; ++h) stageA(0, 0, h);
    stageB(0, 0, 0); stageB(0, 0, 1);
    #pragma unroll
    for (int h = 0; h < MH; ++h) stageA(1, BK, h);
    stageB(1, BK, 0); stageB(1, BK, 1);
    if constexpr (MH == 2) asm volatile("s_waitcnt vmcnt(4)" ::: "memory");
    else                   asm volatile("s_waitcnt vmcnt(3)" ::: "memory");
    __builtin_amdgcn_s_barrier();

    short8 af[2 * MH], bf[4];
    int cur = 0;
    for (int kt = 0; kt < NI; ++kt) {
        const unsigned short* bufA = lds + cur * BUFS;
        const unsigned short* bufB = bufA + 8192;
        const int  stg  = (cur + 2 >= 3) ? cur - 1 : cur + 2;
        const int  k2   = (kt + 2) * BK;
        const bool doSt = (kt + 2 < NI);

        // ---- phase 0: m-half 0, all N ----
        #pragma unroll
        for (int u = 0; u < 2 * MH; ++u)
            af[u] = *(const short8*)(bufA + (wy * (64 * MH) + u * 16 + lm) * 32 + sq8);
        #pragma unroll
        for (int j = 0; j < 4; ++j)
            bf[j] = *(const short8*)(bufB + (wx * 64 + j * 16 + lm) * 32 + sq8);
        if (doSt) {
            stageA(stg, k2, 0);
            if constexpr (MH == 2) stageA(stg, k2, 1); else stageB(stg, k2, 0);
        }
        __builtin_amdgcn_s_barrier();
        __builtin_amdgcn_s_setprio(1);
        #pragma unroll
        for (int u = 0; u < 2 * MH; ++u)
            #pragma unroll
            for (int j = 0; j < 4; ++j)
                acc[u][j] = __builtin_amdgcn_mfma_f32_16x16x32_bf16(af[u], bf[j], acc[u][j], 0, 0, 0);
        __builtin_amdgcn_s_setprio(0);
        __builtin_amdgcn_s_barrier();

        // ---- phase 1: m-half 1, all N (bf reused) ----
        #pragma unroll
        for (int u = 0; u < 2 * MH; ++u)
            af[u] = *(const short8*)(bufA + (wy * (64 * MH) + (2 * MH + u) * 16 + lm) * 32 + sq8);
        if (doSt) {
            if constexpr (MH == 2) { stageB(stg, k2, 0); stageB(stg, k2, 1); }
            else                   stageB(stg, k2, 1);
        }
        __builtin_amdgcn_s_barrier();
        __builtin_amdgcn_s_setprio(1);
        #pragma unroll
        for (int u = 0; u < 2 * MH; ++u)
            #pragma unroll
            for (int j = 0; j < 4; ++j)
                acc[2 * MH + u][j] = __builtin_amdgcn_mfma_f32_16x16x32_bf16(af[u], bf[j], acc[2 * MH + u][j], 0, 0, 0);
        __builtin_amdgcn_s_setprio(0);
        // counted wait: retire tile kt+1's loads, keep kt+2's in flight.
        if (kt == NI - 2) { WAITVM0; }
        else if (kt < NI - 2) {
            if constexpr (MH == 2) asm volatile("s_waitcnt vmcnt(4)" ::: "memory");
            else                   asm volatile("s_waitcnt vmcnt(3)" ::: "memory");
        }
        __builtin_amdgcn_s_barrier();

        cur = (cur == 2) ? 0 : cur + 1;
    }
    asm volatile("" ::: "memory");

    // ---- coalesced epilogue: per-wave LDS bounce, PADDED stride 68 ----
    unsigned short* wbuf = lds + (NI % 3) * BUFS + wave * 1088;   // 16 x 68
    float bvj[4];
    #pragma unroll
    for (int j = 0; j < 4; ++j) bvj[j] = bias[col0 + wx * 64 + j * 16 + lm];
    #pragma unroll
    for (int i = 0; i < 4 * MH; ++i) {
        #pragma unroll
        for (int j = 0; j < 4; ++j) {
            #pragma unroll
            for (int r = 0; r < 4; ++r)
                wbuf[(quad * 4 + r) * 68 + j * 16 + lm] = f32_to_bf16_rn(acc[i][j][r] + bvj[j]);
        }
        asm volatile("s_waitcnt lgkmcnt(0)" ::: "memory");  // cross-lane RAW
        #pragma unroll
        for (int p = 0; p < 2; ++p) {
            const int lrow  = p * 8 + (lane >> 3);
            const int lcol8 = (lane & 7) * 8;
            short8 v = lds_ld8(&wbuf[lrow * 68 + lcol8]);
            *(short8*)(Cb + (size_t)(row0 + wy * (64 * MH) + i * 16 + lrow) * N +
                       col0 + wx * 64 + lcol8) = v;
        }
        asm volatile("s_waitcnt lgkmcnt(0)" ::: "memory");  // WAR before next i
    }
}

__global__ __launch_bounds__(512, 1)
void gemm_qkv8p(const unsigned short* __restrict__ A_g,
                const unsigned short* __restrict__ B_g,
                const float* __restrict__ bias,
                unsigned short* __restrict__ Cb)
{
    __shared__ __align__(16) unsigned short lds[3 * 16384];   // 96 KB
    const int bid = blockIdx.x;
    if (bid < 256) {
        const int sid = (bid & 7) * 32 + (bid >> 3);
        qkv_body<2>(A_g, B_g, bias, Cb,
                    (sid >> 3) * 256, (sid & 7) * 256, Cdim, C3, lds);
    } else {
        const int t   = bid - 256;
        const int sid = (t & 7) * 8 + (t >> 3);
        qkv_body<1>(A_g, B_g, bias, Cb, sid * 128, 2048, Cdim, C3, lds);
    }
}

// ---------------------------------------------------------------------------
// bf16 GEMM (proj): out[M,N] = AO @ B^T + bias, fp32 out.  (R9 known-good)
// ---------------------------------------------------------------------------
__global__ __launch_bounds__(256)
void gemm_proj(const unsigned short* __restrict__ AO_g,
               const unsigned short* __restrict__ B_g,
               const float* __restrict__ bias,
               float* __restrict__ C,
               int M, int N, int K)
{
    __shared__ __align__(16) unsigned short Ah[2][128 * 32];
    __shared__ __align__(16) unsigned short Bh[2][128 * 32];

    const int tid  = threadIdx.x;
    const int wave = tid >> 6;
    const int lane = tid & 63;
    const int lm   = lane & 15;
    const int quad = lane >> 4;
    const int wy   = wave >> 1, wx = wave & 1;
    const int row0 = blockIdx.y * 128;
    const int col0 = blockIdx.x * 128;

    const int sr  = lane >> 2;
    const int skp = (lane & 3) * 8;
    const int NI  = K / 32;

    floatx4 acc[4][4] = {};

    {
        const int head0 = skp >> 6, off0 = skp & 63;
        #pragma unroll
        for (int s = 0; s < 2; ++s) {
            const int r = (wave * 2 + s) * 16 + sr;
            GLOAD_LDS16(AO_g + (size_t)head0 * (Mrows * HD) + (size_t)(row0 + r) * HD + off0,
                        &Ah[0][r * 32 + skp]);
            GLOAD_LDS16(B_g + (size_t)(col0 + r) * K + skp, &Bh[0][r * 32 + skp]);
        }
    }
    __syncthreads();

    for (int kt = 0; kt < NI; ++kt) {
        const int cur = kt & 1, nxt = cur ^ 1;

        if (kt + 1 < NI) {
            const int k0   = (kt + 1) * 32;
            const int kk   = k0 + skp;
            const int head = kk >> 6;          // HD = 64
            const int off  = kk & 63;
            #pragma unroll
            for (int s = 0; s < 2; ++s) {
                const int r = (wave * 2 + s) * 16 + sr;
                GLOAD_LDS16(AO_g + (size_t)head * (Mrows * HD) + (size_t)(row0 + r) * HD + off,
                            &Ah[nxt][r * 32 + skp]);
                GLOAD_LDS16(B_g + (size_t)(col0 + r) * K + k0 + skp, &Bh[nxt][r * 32 + skp]);
            }
        }

        short8 af[4];
        #pragma unroll
        for (int i = 0; i < 4; ++i)
            af[i] = *(const short8*)&Ah[cur][(wy * 64 + i * 16 + lm) * 32 + quad * 8];
        #pragma unroll
        for (int j = 0; j < 4; ++j) {
            short8 bfj = *(const short8*)&Bh[cur][(wx * 64 + j * 16 + lm) * 32 + quad * 8];
            #pragma unroll
            for (int i = 0; i < 4; ++i)
                acc[i][j] = __builtin_amdgcn_mfma_f32_16x16x32_bf16(af[i], bfj, acc[i][j], 0, 0, 0);
        }

        __syncthreads();               // single barrier: orders stage->read
    }

    #pragma unroll
    for (int j = 0; j < 4; ++j) {
        const int col = col0 + wx * 64 + j * 16 + lm;
        const float bv = bias[col];
        #pragma unroll
        for (int i = 0; i < 4; ++i) {
            const int rowb = row0 + wy * 64 + i * 16 + quad * 4;
            #pragma unroll
            for (int r = 0; r < 4; ++r)
                C[(size_t)(rowb + r) * N + col] = acc[i][j][r] + bv;
        }
    }
}

// ---------------------------------------------------------------------------
// Pure-bf16 MFMA flash attention, R15 (fixed compile: memcpy instead of
// bit_cast on __hip_bfloat162; otherwise identical to the R15 design).
//   Value path = EXACT Round-2-verified R11: __expf(S*scale + madd),
//   sequential lsum accumulation, same Ph byte layout.
//   Changes vs R11 (both correct by construction):
//   1. P -> bf16 pair conversion via __float22bfloat162_rn (vendor header;
//      compiler-selected instruction, struct layout pins p0 -> low ushort).
//   2. Block-uniform mask-skip: wave 0 flags tiles with NO masked keys
//      (always true for this input); drops 16 maskadd LDS reads + 16 adds
//      per tile-lane. madd=0 => arithmetic identical.
//   Hand-asm cvt_pk + exp2-domain from R12-R14 are fully reverted.
// ---------------------------------------------------------------------------
__global__ __launch_bounds__(256, 2)
void attn_bf16(const unsigned short* __restrict__ qkv,
               const int* __restrict__ mask,
               unsigned short* __restrict__ outh)
{
    constexpr int LDW = 68;
    constexpr int NT  = Tseq / 64;     // 16 K-tiles
    __shared__ __align__(16) unsigned short Kh[2][64 * LDW];
    __shared__ __align__(16) unsigned short Vh[2][64 * LDW];   // V^T [d][k]
    __shared__ __align__(16) unsigned short Ph[128 * LDW];
    __shared__ float maskadd[2][64];
    __shared__ int   mflag[2];         // 1 = no masked keys in this tile

    const int tid  = threadIdx.x;
    const int wave = tid >> 6;
    const int lane = tid & 63;
    const int lm   = lane & 15;
    const int quad = lane >> 4;
    const int idx  = blockIdx.x;
    const int bh   = idx % (Bsz * NH);
    const int qb   = idx / (Bsz * NH);
    const int b    = bh / NH;
    const int h    = bh % NH;
    const int q0   = qb * 128;
    const float scale = 0.125f;        // 1/sqrt(64)

    // Q fragments (B-layout: n=lm, k=quad*8+j) straight from global
    short8 qf[2][2];
    #pragma unroll
    for (int mt = 0; mt < 2; ++mt) {
        const size_t qrow = (size_t)(b * Tseq + q0 + wave * 32 + mt * 16 + lm) * C3 + h * HD;
        #pragma unroll
        for (int kf = 0; kf < 2; ++kf)
            qf[mt][kf] = *(const short8*)(qkv + qrow + kf * 32 + quad * 8);
    }

    const int sr0 = (tid & 31) * 2;    // k-row pair
    const int sc  = (tid >> 5) * 8;    // 8 dims

    short8 kh0, kh1, vh0, vh1;
    float  mreg = 0.f;

    // --- prefetch + store tile 0 into buf 0 ---
    {
        const size_t g0 = (size_t)(b * Tseq + sr0) * C3 + Cdim + h * HD + sc;
        kh0 = *(const short8*)(qkv + g0);
        kh1 = *(const short8*)(qkv + g0 + C3);
        vh0 = *(const short8*)(qkv + g0 + Cdim);
        vh1 = *(const short8*)(qkv + g0 + Cdim + C3);
        lds_st8(&Kh[0][sr0 * LDW + sc], kh0);
        lds_st8(&Kh[0][(sr0 + 1) * LDW + sc], kh1);
        #pragma unroll
        for (int i = 0; i < 8; ++i) {
            unsigned int pv = (unsigned int)(unsigned short)vh0[i] |
                              ((unsigned int)(unsigned short)vh1[i] << 16);
            *(unsigned int*)&Vh[0][(sc + i) * LDW + sr0] = pv;
        }
        if (tid < 64) {
            mreg = (mask[b * Tseq + tid] == 0) ? -1e30f : 0.0f;
            const int f = __all(mreg == 0.0f);
            maskadd[0][tid] = mreg;
            if (tid == 0) mflag[0] = f;
        }
    }
    __syncthreads();

    floatx4 O[2][4] = {};              // [m][d-tile]; lane: q=lm, d=quad*4+r
    float lsum[2] = {0.f, 0.f};

    for (int kt = 0; kt < NT; ++kt) {
        const int cur = kt & 1;
        const int nxt = cur ^ 1;
        const unsigned short* Khc = Kh[cur];
        const unsigned short* Vhc = Vh[cur];

        // ---- issue prefetch for tile kt+1 early (latency behind compute) ----
        if (kt + 1 < NT) {
            const size_t g0 = (size_t)(b * Tseq + (kt + 1) * 64 + sr0) * C3 + Cdim + h * HD + sc;
            kh0 = *(const short8*)(qkv + g0);
            kh1 = *(const short8*)(qkv + g0 + C3);
            vh0 = *(const short8*)(qkv + g0 + Cdim);
            vh1 = *(const short8*)(qkv + g0 + Cdim + C3);
            if (tid < 64) mreg = (mask[b * Tseq + (kt + 1) * 64 + tid] == 0) ? -1e30f : 0.0f;
        }

        // ---- S^T = K Q^T : D[k][q], lane: q=lm, k=quad*4+r ----
        floatx4 S[2][4] = {};
        #pragma unroll
        for (int kf = 0; kf < 2; ++kf) {
            short8 kh[4];
            #pragma unroll
            for (int nt = 0; nt < 4; ++nt)
                kh[nt] = lds_ld8(&Khc[(nt * 16 + lm) * LDW + kf * 32 + quad * 8]);
            #pragma unroll
            for (int mt = 0; mt < 2; ++mt)
                #pragma unroll
                for (int nt = 0; nt < 4; ++nt)
                    S[mt][nt] = __builtin_amdgcn_mfma_f32_16x16x32_bf16(kh[nt], qf[mt][kf], S[mt][nt], 0, 0, 0);
        }

        const int nomask = mflag[cur];   // block-uniform

        // ---- softmax numerator (R11 value path), packed P store ----
        if (nomask) {
            #pragma unroll
            for (int mt = 0; mt < 2; ++mt) {
                const int prow = (wave * 32 + mt * 16 + lm) * LDW;
                #pragma unroll
                for (int nt = 0; nt < 4; ++nt) {
                    float p0 = __expf(S[mt][nt][0] * scale);
                    float p1 = __expf(S[mt][nt][1] * scale);
                    float p2 = __expf(S[mt][nt][2] * scale);
                    float p3 = __expf(S[mt][nt][3] * scale);
                    lsum[mt] += p0; lsum[mt] += p1;
                    lsum[mt] += p2; lsum[mt] += p3;
                    uint2 pk2;
                    pk2.x = pack_bf16x2_rn(p0, p1);
                    pk2.y = pack_bf16x2_rn(p2, p3);
                    *(uint2*)&Ph[prow + nt * 16 + quad * 4] = pk2;
                }
            }
        } else {
            float madd[4][4];
            #pragma unroll
            for (int nt = 0; nt < 4; ++nt)
                #pragma unroll
                for (int r = 0; r < 4; ++r)
                    madd[nt][r] = maskadd[cur][nt * 16 + quad * 4 + r];
            #pragma unroll
            for (int mt = 0; mt < 2; ++mt) {
                const int prow = (wave * 32 + mt * 16 + lm) * LDW;
                #pragma unroll
                for (int nt = 0; nt < 4; ++nt) {
                    float p0 = __expf(S[mt][nt][0] * scale + madd[nt][0]);
                    float p1 = __expf(S[mt][nt][1] * scale + madd[nt][1]);
                    float p2 = __expf(S[mt][nt][2] * scale + madd[nt][2]);
                    float p3 = __expf(S[mt][nt][3] * scale + madd[nt][3]);
                    lsum[mt] += p0; lsum[mt] += p1;
                    lsum[mt] += p2; lsum[mt] += p3;
                    uint2 pk2;
                    pk2.x = pack_bf16x2_rn(p0, p1);
                    pk2.y = pack_bf16x2_rn(p2, p3);
                    *(uint2*)&Ph[prow + nt * 16 + quad * 4] = pk2;
                }
            }
        }

        // ---- cross-lane fence before reading Ph bytes other quads wrote ----
        LDS_XLANE_FENCE;

        // ---- O^T += V^T P^T (P wave-private) ----
        #pragma unroll
        for (int kf = 0; kf < 2; ++kf) {
            short8 pf[2];
            #pragma unroll
            for (int mt = 0; mt < 2; ++mt)
                pf[mt] = lds_ld8(&Ph[(wave * 32 + mt * 16 + lm) * LDW + kf * 32 + quad * 8]);
            #pragma unroll
            for (int dt = 0; dt < 4; ++dt) {
                short8 vh = lds_ld8(&Vhc[(dt * 16 + lm) * LDW + kf * 32 + quad * 8]);
                #pragma unroll
                for (int mt = 0; mt < 2; ++mt)
                    O[mt][dt] = __builtin_amdgcn_mfma_f32_16x16x32_bf16(vh, pf[mt], O[mt][dt], 0, 0, 0);
            }
        }

        // ---- store prefetched tile into the other buffer ----
        if (kt + 1 < NT) {
            lds_st8(&Kh[nxt][sr0 * LDW + sc], kh0);
            lds_st8(&Kh[nxt][(sr0 + 1) * LDW + sc], kh1);
            #pragma unroll
            for (int i = 0; i < 8; ++i) {
                unsigned int pv = (unsigned int)(unsigned short)vh0[i] |
                                  ((unsigned int)(unsigned short)vh1[i] << 16);
                *(unsigned int*)&Vh[nxt][(sc + i) * LDW + sr0] = pv;
            }
            if (tid < 64) {
                const int f = __all(mreg == 0.0f);
                maskadd[nxt][tid] = mreg;
                if (tid == 0) mflag[nxt] = f;
            }
        }
        __syncthreads();               // single barrier: orders store->read
    }

    // ---- final l reduction across quads, normalize, head-major write ----
    #pragma unroll
    for (int mt = 0; mt < 2; ++mt) {
        lsum[mt] += __shfl_xor(lsum[mt], 16);
        lsum[mt] += __shfl_xor(lsum[mt], 32);
        const float inv_l = 1.0f / lsum[mt];
        const size_t row = (size_t)h * (Mrows * HD) +
                           (size_t)(b * Tseq + q0 + wave * 32 + mt * 16 + lm) * HD;
        #pragma unroll
        for (int dt = 0; dt < 4; ++dt) {
            ushort4 hv;
            unsigned short* hp = &hv.x;
            #pragma unroll
            for (int r = 0; r < 4; ++r)
                hp[r] = f32_to_bf16_rn(O[mt][dt][r] * inv_l);
            *(ushort4*)(outh + row + dt * 16 + quad * 4) = hv;
        }
    }
}

// ---------------------------------------------------------------------------
extern "C" void kernel_launch(void* const* d_in, const int* in_sizes, int n_in,
                              void* d_out, int out_size, void* d_ws, size_t ws_size,
                              hipStream_t stream)
{
    const float* x      = (const float*)d_in[0];
    const int*   mask   = (const int*)  d_in[1];
    const float* W_attn = (const float*)d_in[2];
    const float* b_attn = (const float*)d_in[3];
    const float* W_proj = (const float*)d_in[4];
    const float* b_proj = (const float*)d_in[5];
    float* out = (float*)d_out;

    // workspace (~55 MB)
    unsigned short* xh    = (unsigned short*)d_ws;               // [8192][768]
    unsigned short* wat_h = xh    + (size_t)Mrows * Cdim;        // W_attn^T
    unsigned short* wpt_h = wat_h + (size_t)C3 * Cdim;           // W_proj^T
    unsigned short* qkvh  = wpt_h + (size_t)Cdim * Cdim;         // [8192][2304]
    unsigned short* aoh   = xh;    // reuse: xh dead after gemm1; [12][8192][64]

    dim3 blk(256);

    to_bf16<<<dim3(Mrows * Cdim / 4 / 256), blk, 0, stream>>>(x, xh, Mrows * Cdim / 4);
    transpose_bf16<<<dim3(C3 / 32, Cdim / 32), blk, 0, stream>>>(W_attn, wat_h, Cdim, C3);
    transpose_bf16<<<dim3(Cdim / 32, Cdim / 32), blk, 0, stream>>>(W_proj, wpt_h, Cdim, Cdim);

    // qkv = x @ W_attn + b_attn  (bf16 out)
    gemm_qkv8p<<<dim3(320), dim3(512), 0, stream>>>(xh, wat_h, b_attn, qkvh);

    // attention -> head-major bf16
    attn_bf16<<<dim3((Tseq / 128) * Bsz * NH), blk, 0, stream>>>(qkvh, mask, aoh);

    // out = attnout @ W_proj + b_proj (fp32 out)
    gemm_proj<<<dim3(Cdim / 128, Mrows / 128), blk, 0, stream>>>(
        aoh, wpt_h, b_proj, out, Mrows, Cdim, Cdim);
}